// Round 1
// baseline (96925.916 us; speedup 1.0000x reference)
//
#include <hip/hip_runtime.h>
#include <math.h>

// Echo-state network: sequential scan with dense 2048x2048 matvec per step.
// Strategy:
//  - Persistent scan kernel: 256 blocks (1/CU), each owns 8 rows of W held in
//    REGISTERS (64 floats/thread). Per step: all-to-all broadcast of h (8 KB)
//    through LLC using per-value sentinel sync (h stored biased +2, ready iff
//    value >= 0.5; memset-0 / 0xAA poison both read as not-ready).
//  - fc1/fc2 collapse (no nonlinearity between): M = fc2_w @ fc1_w (50x2048),
//    bias c2 = fc2_w@fc1_b + fc2_b - 2*rowsum(M)  (the -2 un-biases states).
//  - Phase 3: memory-bound GEMM states(16384x2048) @ Mt(2048x64pad).

#define SS 16384
#define II 64
#define RR 2048
#define HH 128
#define OO 50
#define OP 64          // padded output dim
#define NBLK 256
#define RPB 8          // rows of W per block
#define NTHR 256
#define KCOLS 16       // h-columns per thread (128 col-groups * 16 = 2048)
#define TT 16          // timesteps per block in out_kernel

static const size_t STATES_BYTES = (size_t)SS * RR * 4;        // 134217728
static const size_t MT_BYTES     = (size_t)RR * OP * 4;        // 524288
static const size_t C2_OFF       = STATES_BYTES + MT_BYTES;
static const size_t RS_OFF       = C2_OFF + 256;
static const size_t WS_NEED      = RS_OFF + 512 + 256;

// ---------------------------------------------------------------------------
// Persistent scan kernel.
// Thread mapping: r4 = tid&1 selects rows [blk*8 + r4*4 .. +3];
// c = tid>>1 in 0..127 owns h-columns {c + 128k, k=0..15}.
// ---------------------------------------------------------------------------
__global__ __launch_bounds__(NTHR)
void scan_kernel(const float* __restrict__ x,
                 const float* __restrict__ Win,
                 const float* __restrict__ W,
                 float* __restrict__ states)
{
    const int tid  = threadIdx.x;
    const int blk  = blockIdx.x;
    const int r4   = tid & 1;
    const int c    = tid >> 1;              // 0..127
    const int row0 = blk * RPB + r4 * 4;
    const int wave = tid >> 6;
    const int lane = tid & 63;

    // W fragment in registers: w[k][j] = W[row0+j][c + 128k]
    float w[KCOLS][4];
#pragma unroll
    for (int k = 0; k < KCOLS; ++k) {
        const int col = c + 128 * k;
#pragma unroll
        for (int j = 0; j < 4; ++j)
            w[k][j] = W[(size_t)(row0 + j) * RR + col];
    }
    // Win fragment (input projection folded into the step): threads c<64
    float win0 = 0.f, win1 = 0.f, win2 = 0.f, win3 = 0.f;
    if (c < II) {
        win0 = Win[(size_t)(row0 + 0) * II + c];
        win1 = Win[(size_t)(row0 + 1) * II + c];
        win2 = Win[(size_t)(row0 + 2) * II + c];
        win3 = Win[(size_t)(row0 + 3) * II + c];
    }

    __shared__ float h_old[RPB];
    __shared__ float partial[RPB][4];
    if (tid < RPB) h_old[tid] = 0.f;
    __syncthreads();

    for (int t = 0; t < SS; ++t) {
        float acc0 = 0.f, acc1 = 0.f, acc2 = 0.f, acc3 = 0.f;

        // Independent prefetchable input load (pristine buffer, no sync needed)
        float xv = 0.f;
        if (c < II) xv = x[t * II + c];

        if (t > 0) {
            const float* hp = states + (size_t)(t - 1) * RR;
            float v[KCOLS];
            // First pass: 16 independent loads in flight (pipelined latency)
#pragma unroll
            for (int k = 0; k < KCOLS; ++k)
                v[k] = __hip_atomic_load(hp + c + 128 * k,
                                         __ATOMIC_RELAXED, __HIP_MEMORY_SCOPE_AGENT);
            // Retry stragglers per value, then FMA against register-held W
#pragma unroll
            for (int k = 0; k < KCOLS; ++k) {
                float val = v[k];
                while (val < 0.5f)   // sentinel: ready values are in (1,3)
                    val = __hip_atomic_load(hp + c + 128 * k,
                                            __ATOMIC_RELAXED, __HIP_MEMORY_SCOPE_AGENT);
                val -= 2.0f;         // un-bias
                acc0 += w[k][0] * val;
                acc1 += w[k][1] * val;
                acc2 += w[k][2] * val;
                acc3 += w[k][3] * val;
            }
        }
        if (c < II) {
            acc0 += win0 * xv; acc1 += win1 * xv;
            acc2 += win2 * xv; acc3 += win3 * xv;
        }

        // Reduce over same-parity lanes (c-dim) within each wave.
#pragma unroll
        for (int off = 2; off <= 32; off <<= 1) {
            acc0 += __shfl_xor(acc0, off, 64);
            acc1 += __shfl_xor(acc1, off, 64);
            acc2 += __shfl_xor(acc2, off, 64);
            acc3 += __shfl_xor(acc3, off, 64);
        }
        if (lane < 2) {              // lane0: rows 0-3, lane1: rows 4-7
            partial[r4 * 4 + 0][wave] = acc0;
            partial[r4 * 4 + 1][wave] = acc1;
            partial[r4 * 4 + 2][wave] = acc2;
            partial[r4 * 4 + 3][wave] = acc3;
        }
        __syncthreads();

        if (tid < RPB) {
            float u = partial[tid][0] + partial[tid][1] +
                      partial[tid][2] + partial[tid][3];
            // fast tanh via exp (cheaper than libm tanhf on the critical path)
            u = fminf(fmaxf(u, -30.f), 30.f);
            float e  = __expf(2.f * u);
            float th = (e - 1.f) / (e + 1.f);
            float hn = 0.5f * h_old[tid] + 0.5f * th;
            h_old[tid] = hn;
            __hip_atomic_store(&states[(size_t)t * RR + blk * RPB + tid],
                               hn + 2.0f,
                               __ATOMIC_RELAXED, __HIP_MEMORY_SCOPE_AGENT);
        }
        __syncthreads();             // protect partial[] reuse next step
    }
}

// ---------------------------------------------------------------------------
// rowsum of fc1_w rows: rs[h] = sum_r fc1_w[h][r]
// ---------------------------------------------------------------------------
__global__ void k_rowsum(const float* __restrict__ fc1w, float* __restrict__ rs)
{
    const int h = blockIdx.x;
    const int tid = threadIdx.x;
    float a = 0.f;
    for (int r = tid; r < RR; r += 256) a += fc1w[(size_t)h * RR + r];
#pragma unroll
    for (int off = 1; off <= 32; off <<= 1) a += __shfl_xor(a, off, 64);
    __shared__ float red[4];
    if ((tid & 63) == 0) red[tid >> 6] = a;
    __syncthreads();
    if (tid == 0) rs[h] = red[0] + red[1] + red[2] + red[3];
}

// ---------------------------------------------------------------------------
// Mt[r][o] = sum_h fc2_w[o][h] * fc1_w[h][r]   (o padded to 64, zeros)
// ---------------------------------------------------------------------------
__global__ void k_mt(const float* __restrict__ fc1w,
                     const float* __restrict__ fc2w,
                     float* __restrict__ Mt)
{
    __shared__ float w2[OO][HH + 1];   // +1 pad: conflict-free o-varying reads
    const int o = threadIdx.x;         // 64
    const int r = blockIdx.x;          // 2048
    for (int i = o; i < OO * HH; i += 64) w2[i / HH][i % HH] = fc2w[i];
    __syncthreads();
    float a = 0.f;
    if (o < OO) {
        for (int h = 0; h < HH; ++h)
            a += w2[o][h] * fc1w[(size_t)h * RR + r];   // fc1w: scalar broadcast
    }
    Mt[r * OP + o] = a;
}

// ---------------------------------------------------------------------------
// c2[o] = fc2_b[o] + sum_h fc2_w[o][h]*(fc1_b[h] - 2*rs[h])
// (the -2*rs term un-biases the +2-biased stored states)
// ---------------------------------------------------------------------------
__global__ void k_c2(const float* __restrict__ fc2w,
                     const float* __restrict__ fc2b,
                     const float* __restrict__ fc1b,
                     const float* __restrict__ rs,
                     float* __restrict__ c2)
{
    const int o = threadIdx.x;  // 64
    float a = 0.f;
    if (o < OO) {
        for (int h = 0; h < HH; ++h)
            a += fc2w[o * HH + h] * (fc1b[h] - 2.f * rs[h]);
        a += fc2b[o];
    }
    c2[o] = a;
}

// ---------------------------------------------------------------------------
// out[t][o] = sum_r Mt[r][o] * states_biased[t][r] + c2[o]
// Block: 16 timesteps. Thread: o = tid&63, tl = tid>>6, handles t = t0+tl+4m.
// ---------------------------------------------------------------------------
__global__ __launch_bounds__(256)
void out_kernel(const float* __restrict__ sb,
                const float* __restrict__ Mt,
                const float* __restrict__ c2,
                float* __restrict__ out)
{
    const int tid = threadIdx.x;
    const int o   = tid & 63;
    const int tl  = tid >> 6;          // 0..3
    const int t0  = blockIdx.x * TT;
    float acc[4] = {0.f, 0.f, 0.f, 0.f};
    const float* s0 = sb + (size_t)t0 * RR;

    for (int r = 0; r < RR; r += 4) {
        float4 sv0 = *(const float4*)(s0 + (size_t)(tl + 0)  * RR + r);
        float4 sv1 = *(const float4*)(s0 + (size_t)(tl + 4)  * RR + r);
        float4 sv2 = *(const float4*)(s0 + (size_t)(tl + 8)  * RR + r);
        float4 sv3 = *(const float4*)(s0 + (size_t)(tl + 12) * RR + r);
        float m0 = Mt[(r + 0) * OP + o];
        float m1 = Mt[(r + 1) * OP + o];
        float m2 = Mt[(r + 2) * OP + o];
        float m3 = Mt[(r + 3) * OP + o];
        acc[0] += m0 * sv0.x + m1 * sv0.y + m2 * sv0.z + m3 * sv0.w;
        acc[1] += m0 * sv1.x + m1 * sv1.y + m2 * sv1.z + m3 * sv1.w;
        acc[2] += m0 * sv2.x + m1 * sv2.y + m2 * sv2.z + m3 * sv2.w;
        acc[3] += m0 * sv3.x + m1 * sv3.y + m2 * sv3.z + m3 * sv3.w;
    }
    if (o < OO) {
        const float cc = c2[o];
#pragma unroll
        for (int m = 0; m < 4; ++m) {
            const int t = t0 + tl + 4 * m;
            out[(size_t)t * OO + o] = acc[m] + cc;
        }
    }
}

extern "C" void kernel_launch(void* const* d_in, const int* in_sizes, int n_in,
                              void* d_out, int out_size, void* d_ws, size_t ws_size,
                              hipStream_t stream)
{
    const float* x    = (const float*)d_in[0];
    const float* Win  = (const float*)d_in[1];
    const float* W    = (const float*)d_in[2];
    const float* fc1w = (const float*)d_in[3];
    const float* fc1b = (const float*)d_in[4];
    const float* fc2w = (const float*)d_in[5];
    const float* fc2b = (const float*)d_in[6];
    float* out = (float*)d_out;

    if (ws_size < WS_NEED) return;  // cannot run without the states buffer

    char*  ws     = (char*)d_ws;
    float* states = (float*)ws;
    float* Mt     = (float*)(ws + STATES_BYTES);
    float* c2     = (float*)(ws + C2_OFF);
    float* rs     = (float*)(ws + RS_OFF);

    // Sentinel init: 0.0f < 0.5f means "not ready" for every h value.
    hipMemsetAsync(states, 0, STATES_BYTES, stream);

    k_rowsum<<<HH, 256, 0, stream>>>(fc1w, rs);
    k_mt<<<RR, 64, 0, stream>>>(fc1w, fc2w, Mt);
    k_c2<<<1, 64, 0, stream>>>(fc2w, fc2b, fc1b, rs, c2);

    scan_kernel<<<NBLK, NTHR, 0, stream>>>(x, Win, W, states);

    out_kernel<<<SS / TT, 256, 0, stream>>>(states, Mt, c2, out);
}

// Round 2
// 33827.417 us; speedup vs baseline: 2.8653x; 2.8653x over previous
//
#include <hip/hip_runtime.h>
#include <math.h>

// Echo-state network: sequential scan with dense 2048x2048 matvec per step.
// Strategy:
//  - Persistent scan kernel: 256 blocks (1/CU), each owns 8 rows of W held in
//    REGISTERS (64 floats/thread). Per step: all-to-all broadcast of h (8 KB)
//    through LLC using per-value sentinel sync (h stored biased +2, ready iff
//    value >= 0.5; memset-0 / 0xAA poison both read as not-ready).
//  - R1 fix: BATCHED retry. R0's per-value `while(v<0.5) reload` serialized 16
//    dependent LLC round-trips (~7.5us/step measured). Now: check min of all
//    16, and if any not ready re-issue ALL 16 loads back-to-back (independent,
//    single waitcnt) -> each poll round costs ~1 LLC latency, not 16.
//  - fc1/fc2 collapse (no nonlinearity between): M = fc2_w @ fc1_w (50x2048),
//    bias c2 = fc2_w@fc1_b + fc2_b - 2*rowsum(M)  (the -2 un-biases states).
//  - Phase 3: memory-bound GEMM states(16384x2048) @ Mt(2048x64pad).

#define SS 16384
#define II 64
#define RR 2048
#define HH 128
#define OO 50
#define OP 64          // padded output dim
#define NBLK 256
#define RPB 8          // rows of W per block
#define NTHR 256
#define KCOLS 16       // h-columns per thread (128 col-groups * 16 = 2048)
#define TT 16          // timesteps per block in out_kernel

static const size_t STATES_BYTES = (size_t)SS * RR * 4;        // 134217728
static const size_t MT_BYTES     = (size_t)RR * OP * 4;        // 524288
static const size_t C2_OFF       = STATES_BYTES + MT_BYTES;
static const size_t RS_OFF       = C2_OFF + 256;
static const size_t WS_NEED      = RS_OFF + 512 + 256;

// ---------------------------------------------------------------------------
// Persistent scan kernel.
// Thread mapping: r4 = tid&1 selects rows [blk*8 + r4*4 .. +3];
// c = tid>>1 in 0..127 owns h-columns {c + 128k, k=0..15}.
// ---------------------------------------------------------------------------
__global__ __launch_bounds__(NTHR)
void scan_kernel(const float* __restrict__ x,
                 const float* __restrict__ Win,
                 const float* __restrict__ W,
                 float* __restrict__ states)
{
    const int tid  = threadIdx.x;
    const int blk  = blockIdx.x;
    const int r4   = tid & 1;
    const int c    = tid >> 1;              // 0..127
    const int row0 = blk * RPB + r4 * 4;
    const int wave = tid >> 6;
    const int lane = tid & 63;

    // W fragment in registers: w[k][j] = W[row0+j][c + 128k]
    float w[KCOLS][4];
#pragma unroll
    for (int k = 0; k < KCOLS; ++k) {
        const int col = c + 128 * k;
#pragma unroll
        for (int j = 0; j < 4; ++j)
            w[k][j] = W[(size_t)(row0 + j) * RR + col];
    }
    // Win fragment (input projection folded into the step): threads c<64
    float win0 = 0.f, win1 = 0.f, win2 = 0.f, win3 = 0.f;
    if (c < II) {
        win0 = Win[(size_t)(row0 + 0) * II + c];
        win1 = Win[(size_t)(row0 + 1) * II + c];
        win2 = Win[(size_t)(row0 + 2) * II + c];
        win3 = Win[(size_t)(row0 + 3) * II + c];
    }

    __shared__ float h_old[RPB];
    __shared__ float partial[RPB][4];
    if (tid < RPB) h_old[tid] = 0.f;
    __syncthreads();

    for (int t = 0; t < SS; ++t) {
        float acc0 = 0.f, acc1 = 0.f, acc2 = 0.f, acc3 = 0.f;

        // Independent prefetchable input load (pristine buffer, no sync needed)
        float xv = 0.f;
        if (c < II) xv = x[t * II + c];

        if (t > 0) {
            const float* hp = states + (size_t)(t - 1) * RR;
            float v[KCOLS];
            // First pass: 16 independent loads in flight (pipelined latency)
#pragma unroll
            for (int k = 0; k < KCOLS; ++k)
                v[k] = __hip_atomic_load(hp + c + 128 * k,
                                         __ATOMIC_RELAXED, __HIP_MEMORY_SCOPE_AGENT);
            // Batched poll: if ANY value not ready, re-issue ALL 16 loads
            // (independent -> one LLC latency per round, not 16).
            for (;;) {
                float mn = fminf(fminf(fminf(v[0],  v[1]),  fminf(v[2],  v[3])),
                                 fminf(fminf(v[4],  v[5]),  fminf(v[6],  v[7])));
                mn = fminf(mn,
                     fminf(fminf(fminf(v[8],  v[9]),  fminf(v[10], v[11])),
                           fminf(fminf(v[12], v[13]), fminf(v[14], v[15]))));
                if (mn >= 0.5f) break;   // sentinel: ready values are in (1,3)
#pragma unroll
                for (int k = 0; k < KCOLS; ++k)
                    v[k] = __hip_atomic_load(hp + c + 128 * k,
                                             __ATOMIC_RELAXED, __HIP_MEMORY_SCOPE_AGENT);
            }
            // FMA against register-held W
#pragma unroll
            for (int k = 0; k < KCOLS; ++k) {
                const float val = v[k] - 2.0f;   // un-bias
                acc0 += w[k][0] * val;
                acc1 += w[k][1] * val;
                acc2 += w[k][2] * val;
                acc3 += w[k][3] * val;
            }
        }
        if (c < II) {
            acc0 += win0 * xv; acc1 += win1 * xv;
            acc2 += win2 * xv; acc3 += win3 * xv;
        }

        // Reduce over same-parity lanes (c-dim) within each wave.
#pragma unroll
        for (int off = 2; off <= 32; off <<= 1) {
            acc0 += __shfl_xor(acc0, off, 64);
            acc1 += __shfl_xor(acc1, off, 64);
            acc2 += __shfl_xor(acc2, off, 64);
            acc3 += __shfl_xor(acc3, off, 64);
        }
        if (lane < 2) {              // lane0: rows 0-3, lane1: rows 4-7
            partial[r4 * 4 + 0][wave] = acc0;
            partial[r4 * 4 + 1][wave] = acc1;
            partial[r4 * 4 + 2][wave] = acc2;
            partial[r4 * 4 + 3][wave] = acc3;
        }
        __syncthreads();

        if (tid < RPB) {
            float u = partial[tid][0] + partial[tid][1] +
                      partial[tid][2] + partial[tid][3];
            // fast tanh via exp (cheaper than libm tanhf on the critical path)
            u = fminf(fmaxf(u, -30.f), 30.f);
            float e  = __expf(2.f * u);
            float th = (e - 1.f) / (e + 1.f);
            float hn = 0.5f * h_old[tid] + 0.5f * th;
            h_old[tid] = hn;
            __hip_atomic_store(&states[(size_t)t * RR + blk * RPB + tid],
                               hn + 2.0f,
                               __ATOMIC_RELAXED, __HIP_MEMORY_SCOPE_AGENT);
        }
        __syncthreads();             // protect partial[] reuse next step
    }
}

// ---------------------------------------------------------------------------
// rowsum of fc1_w rows: rs[h] = sum_r fc1_w[h][r]
// ---------------------------------------------------------------------------
__global__ void k_rowsum(const float* __restrict__ fc1w, float* __restrict__ rs)
{
    const int h = blockIdx.x;
    const int tid = threadIdx.x;
    float a = 0.f;
    for (int r = tid; r < RR; r += 256) a += fc1w[(size_t)h * RR + r];
#pragma unroll
    for (int off = 1; off <= 32; off <<= 1) a += __shfl_xor(a, off, 64);
    __shared__ float red[4];
    if ((tid & 63) == 0) red[tid >> 6] = a;
    __syncthreads();
    if (tid == 0) rs[h] = red[0] + red[1] + red[2] + red[3];
}

// ---------------------------------------------------------------------------
// Mt[r][o] = sum_h fc2_w[o][h] * fc1_w[h][r]   (o padded to 64, zeros)
// ---------------------------------------------------------------------------
__global__ void k_mt(const float* __restrict__ fc1w,
                     const float* __restrict__ fc2w,
                     float* __restrict__ Mt)
{
    __shared__ float w2[OO][HH + 1];   // +1 pad: conflict-free o-varying reads
    const int o = threadIdx.x;         // 64
    const int r = blockIdx.x;          // 2048
    for (int i = o; i < OO * HH; i += 64) w2[i / HH][i % HH] = fc2w[i];
    __syncthreads();
    float a = 0.f;
    if (o < OO) {
        for (int h = 0; h < HH; ++h)
            a += w2[o][h] * fc1w[(size_t)h * RR + r];   // fc1w: scalar broadcast
    }
    Mt[r * OP + o] = a;
}

// ---------------------------------------------------------------------------
// c2[o] = fc2_b[o] + sum_h fc2_w[o][h]*(fc1_b[h] - 2*rs[h])
// (the -2*rs term un-biases the +2-biased stored states)
// ---------------------------------------------------------------------------
__global__ void k_c2(const float* __restrict__ fc2w,
                     const float* __restrict__ fc2b,
                     const float* __restrict__ fc1b,
                     const float* __restrict__ rs,
                     float* __restrict__ c2)
{
    const int o = threadIdx.x;  // 64
    float a = 0.f;
    if (o < OO) {
        for (int h = 0; h < HH; ++h)
            a += fc2w[o * HH + h] * (fc1b[h] - 2.f * rs[h]);
        a += fc2b[o];
    }
    c2[o] = a;
}

// ---------------------------------------------------------------------------
// out[t][o] = sum_r Mt[r][o] * states_biased[t][r] + c2[o]
// Block: 16 timesteps. Thread: o = tid&63, tl = tid>>6, handles t = t0+tl+4m.
// ---------------------------------------------------------------------------
__global__ __launch_bounds__(256)
void out_kernel(const float* __restrict__ sb,
                const float* __restrict__ Mt,
                const float* __restrict__ c2,
                float* __restrict__ out)
{
    const int tid = threadIdx.x;
    const int o   = tid & 63;
    const int tl  = tid >> 6;          // 0..3
    const int t0  = blockIdx.x * TT;
    float acc[4] = {0.f, 0.f, 0.f, 0.f};
    const float* s0 = sb + (size_t)t0 * RR;

    for (int r = 0; r < RR; r += 4) {
        float4 sv0 = *(const float4*)(s0 + (size_t)(tl + 0)  * RR + r);
        float4 sv1 = *(const float4*)(s0 + (size_t)(tl + 4)  * RR + r);
        float4 sv2 = *(const float4*)(s0 + (size_t)(tl + 8)  * RR + r);
        float4 sv3 = *(const float4*)(s0 + (size_t)(tl + 12) * RR + r);
        float m0 = Mt[(r + 0) * OP + o];
        float m1 = Mt[(r + 1) * OP + o];
        float m2 = Mt[(r + 2) * OP + o];
        float m3 = Mt[(r + 3) * OP + o];
        acc[0] += m0 * sv0.x + m1 * sv0.y + m2 * sv0.z + m3 * sv0.w;
        acc[1] += m0 * sv1.x + m1 * sv1.y + m2 * sv1.z + m3 * sv1.w;
        acc[2] += m0 * sv2.x + m1 * sv2.y + m2 * sv2.z + m3 * sv2.w;
        acc[3] += m0 * sv3.x + m1 * sv3.y + m2 * sv3.z + m3 * sv3.w;
    }
    if (o < OO) {
        const float cc = c2[o];
#pragma unroll
        for (int m = 0; m < 4; ++m) {
            const int t = t0 + tl + 4 * m;
            out[(size_t)t * OO + o] = acc[m] + cc;
        }
    }
}

extern "C" void kernel_launch(void* const* d_in, const int* in_sizes, int n_in,
                              void* d_out, int out_size, void* d_ws, size_t ws_size,
                              hipStream_t stream)
{
    const float* x    = (const float*)d_in[0];
    const float* Win  = (const float*)d_in[1];
    const float* W    = (const float*)d_in[2];
    const float* fc1w = (const float*)d_in[3];
    const float* fc1b = (const float*)d_in[4];
    const float* fc2w = (const float*)d_in[5];
    const float* fc2b = (const float*)d_in[6];
    float* out = (float*)d_out;

    if (ws_size < WS_NEED) return;  // cannot run without the states buffer

    char*  ws     = (char*)d_ws;
    float* states = (float*)ws;
    float* Mt     = (float*)(ws + STATES_BYTES);
    float* c2     = (float*)(ws + C2_OFF);
    float* rs     = (float*)(ws + RS_OFF);

    // Sentinel init: 0.0f < 0.5f means "not ready" for every h value.
    hipMemsetAsync(states, 0, STATES_BYTES, stream);

    k_rowsum<<<HH, 256, 0, stream>>>(fc1w, rs);
    k_mt<<<RR, 64, 0, stream>>>(fc1w, fc2w, Mt);
    k_c2<<<1, 64, 0, stream>>>(fc2w, fc2b, fc1b, rs, c2);

    scan_kernel<<<NBLK, NTHR, 0, stream>>>(x, Win, W, states);

    out_kernel<<<SS / TT, 256, 0, stream>>>(states, Mt, c2, out);
}

// Round 3
// 30276.627 us; speedup vs baseline: 3.2013x; 1.1173x over previous
//
#include <hip/hip_runtime.h>
#include <math.h>

// Echo-state network: sequential scan with dense 2048x2048 matvec per step.
// R3 design:
//  - Persistent scan: 256 blocks x 256 thr. Each WAVE owns 2 rows of W in
//    registers (32 cols/lane x 2 rows = 64 VGPRs) and is fully autonomous:
//    in-wave butterfly reduce -> tanh -> immediate 2-word store. No LDS
//    partials, no post-reduce barrier (R2's epilogue-after-2-barriers gone).
//  - h broadcast: block-cooperative poll-load of the 2048 h words into a
//    double-buffered LDS tile (8 words/thread, coalesced). Retry rounds
//    re-issue ONLY not-ready values (exec-masked) -> poll traffic ~2MB/step
//    first pass + stragglers, vs R2's 2MB * every round.
//  - Sentinel sync: h stored biased +2 (ready iff >= 0.5); memset-0 and the
//    harness 0xAA poison (-3e-13) both read not-ready. No fences needed.
//  - fc1/fc2 collapse: M = fc2_w@fc1_w, c2 = fc2_w@fc1_b + fc2_b - 2*rowsum(M)
//    (the -2 un-biases stored states). Phase 3: GEMM states @ Mt(2048x64pad).

#define SS 16384
#define II 64
#define RR 2048
#define HH 128
#define OO 50
#define OP 64          // padded output dim
#define NBLK 256
#define NTHR 256
#define TT 16          // timesteps per block in out_kernel

static const size_t STATES_BYTES = (size_t)SS * RR * 4;        // 134217728
static const size_t MT_BYTES     = (size_t)RR * OP * 4;        // 524288
static const size_t C2_OFF       = STATES_BYTES + MT_BYTES;
static const size_t RS_OFF       = C2_OFF + 256;
static const size_t WS_NEED      = RS_OFF + 512 + 256;

// ---------------------------------------------------------------------------
// Persistent scan kernel. Wave w of block b owns rows R0=b*8+2w, R0+1.
// Lane l holds W[R0][l+64k], W[R0+1][l+64k], k=0..31 in registers.
// ---------------------------------------------------------------------------
__global__ __launch_bounds__(NTHR)
void scan_kernel(const float* __restrict__ x,
                 const float* __restrict__ Win,
                 const float* __restrict__ W,
                 float* __restrict__ states)
{
    const int tid  = threadIdx.x;
    const int blk  = blockIdx.x;
    const int wave = tid >> 6;
    const int lane = tid & 63;
    const int R0   = blk * 8 + wave * 2;

    // W fragments in registers
    float w0[32], w1[32];
#pragma unroll
    for (int k = 0; k < 32; ++k) {
        w0[k] = W[(size_t)R0       * RR + lane + 64 * k];
        w1[k] = W[(size_t)(R0 + 1) * RR + lane + 64 * k];
    }
    // Input projection fragments (II == 64 == lanes)
    const float win0 = Win[(size_t)R0       * II + lane];
    const float win1 = Win[(size_t)(R0 + 1) * II + lane];

    __shared__ float hbuf[2][RR];   // double-buffered unbiased h tile

    const int   p    = lane & 1;    // even lanes track row R0, odd R0+1
    float       hold = 0.f;         // h_old for row R0+p (redundant per lane)

    for (int t = 0; t < SS; ++t) {
        // x load: independent of h, issued before the poll hides its latency
        const float xv = x[(size_t)t * II + lane];
        float acc0 = win0 * xv;
        float acc1 = win1 * xv;

        if (t > 0) {
            const float* hp = states + (size_t)(t - 1) * RR;
            float* sb = hbuf[(t - 1) & 1];
            float v[8];
            // First pass: 8 coalesced loads/thread (block covers all 2048)
#pragma unroll
            for (int k = 0; k < 8; ++k)
                v[k] = __hip_atomic_load(hp + tid + 256 * k,
                                         __ATOMIC_RELAXED, __HIP_MEMORY_SCOPE_AGENT);
            // Straggler-only batched retry: re-issue only not-ready values
            // (exec-masked loads, one waitcnt per round).
            for (;;) {
                float mn = fminf(fminf(fminf(v[0], v[1]), fminf(v[2], v[3])),
                                 fminf(fminf(v[4], v[5]), fminf(v[6], v[7])));
                if (mn >= 0.5f) break;   // ready values are in (1,3)
#pragma unroll
                for (int k = 0; k < 8; ++k)
                    if (v[k] < 0.5f)
                        v[k] = __hip_atomic_load(hp + tid + 256 * k,
                                                 __ATOMIC_RELAXED, __HIP_MEMORY_SCOPE_AGENT);
            }
            // Publish unbiased values to LDS (bank = tid%32, 2-way, free)
#pragma unroll
            for (int k = 0; k < 8; ++k)
                sb[tid + 256 * k] = v[k] - 2.0f;
            __syncthreads();           // the ONLY barrier per step

            // Consume: stride-64 LDS reads (2-way aliasing, conflict-free)
#pragma unroll
            for (int k = 0; k < 32; ++k) {
                const float hv = sb[lane + 64 * k];
                acc0 += w0[k] * hv;
                acc1 += w1[k] * hv;
            }
        }

        // In-wave butterfly: all lanes end with both full row sums
#pragma unroll
        for (int off = 1; off <= 32; off <<= 1) {
            acc0 += __shfl_xor(acc0, off, 64);
            acc1 += __shfl_xor(acc1, off, 64);
        }

        // Each lane finishes ONE row (by parity); lanes 0,1 store.
        float u = p ? acc1 : acc0;
        u = fminf(fmaxf(u, -20.f), 20.f);
        const float e  = __expf(2.f * u);
        const float th = (e - 1.f) / (e + 1.f);
        const float hn = 0.5f * hold + 0.5f * th;
        hold = hn;
        if (lane < 2)
            __hip_atomic_store(&states[(size_t)t * RR + R0 + lane], hn + 2.0f,
                               __ATOMIC_RELAXED, __HIP_MEMORY_SCOPE_AGENT);
    }
}

// ---------------------------------------------------------------------------
// rowsum of fc1_w rows: rs[h] = sum_r fc1_w[h][r]
// ---------------------------------------------------------------------------
__global__ void k_rowsum(const float* __restrict__ fc1w, float* __restrict__ rs)
{
    const int h = blockIdx.x;
    const int tid = threadIdx.x;
    float a = 0.f;
    for (int r = tid; r < RR; r += 256) a += fc1w[(size_t)h * RR + r];
#pragma unroll
    for (int off = 1; off <= 32; off <<= 1) a += __shfl_xor(a, off, 64);
    __shared__ float red[4];
    if ((tid & 63) == 0) red[tid >> 6] = a;
    __syncthreads();
    if (tid == 0) rs[h] = red[0] + red[1] + red[2] + red[3];
}

// ---------------------------------------------------------------------------
// Mt[r][o] = sum_h fc2_w[o][h] * fc1_w[h][r]   (o padded to 64, zeros)
// ---------------------------------------------------------------------------
__global__ void k_mt(const float* __restrict__ fc1w,
                     const float* __restrict__ fc2w,
                     float* __restrict__ Mt)
{
    __shared__ float w2[OO][HH + 1];
    const int o = threadIdx.x;         // 64
    const int r = blockIdx.x;          // 2048
    for (int i = o; i < OO * HH; i += 64) w2[i / HH][i % HH] = fc2w[i];
    __syncthreads();
    float a = 0.f;
    if (o < OO) {
        for (int h = 0; h < HH; ++h)
            a += w2[o][h] * fc1w[(size_t)h * RR + r];
    }
    Mt[r * OP + o] = a;
}

// ---------------------------------------------------------------------------
// c2[o] = fc2_b[o] + sum_h fc2_w[o][h]*(fc1_b[h] - 2*rs[h])
// ---------------------------------------------------------------------------
__global__ void k_c2(const float* __restrict__ fc2w,
                     const float* __restrict__ fc2b,
                     const float* __restrict__ fc1b,
                     const float* __restrict__ rs,
                     float* __restrict__ c2)
{
    const int o = threadIdx.x;  // 64
    float a = 0.f;
    if (o < OO) {
        for (int h = 0; h < HH; ++h)
            a += fc2w[o * HH + h] * (fc1b[h] - 2.f * rs[h]);
        a += fc2b[o];
    }
    c2[o] = a;
}

// ---------------------------------------------------------------------------
// out[t][o] = sum_r Mt[r][o] * states_biased[t][r] + c2[o]
// ---------------------------------------------------------------------------
__global__ __launch_bounds__(256)
void out_kernel(const float* __restrict__ sb,
                const float* __restrict__ Mt,
                const float* __restrict__ c2,
                float* __restrict__ out)
{
    const int tid = threadIdx.x;
    const int o   = tid & 63;
    const int tl  = tid >> 6;          // 0..3
    const int t0  = blockIdx.x * TT;
    float acc[4] = {0.f, 0.f, 0.f, 0.f};
    const float* s0 = sb + (size_t)t0 * RR;

    for (int r = 0; r < RR; r += 4) {
        float4 sv0 = *(const float4*)(s0 + (size_t)(tl + 0)  * RR + r);
        float4 sv1 = *(const float4*)(s0 + (size_t)(tl + 4)  * RR + r);
        float4 sv2 = *(const float4*)(s0 + (size_t)(tl + 8)  * RR + r);
        float4 sv3 = *(const float4*)(s0 + (size_t)(tl + 12) * RR + r);
        float m0 = Mt[(r + 0) * OP + o];
        float m1 = Mt[(r + 1) * OP + o];
        float m2 = Mt[(r + 2) * OP + o];
        float m3 = Mt[(r + 3) * OP + o];
        acc[0] += m0 * sv0.x + m1 * sv0.y + m2 * sv0.z + m3 * sv0.w;
        acc[1] += m0 * sv1.x + m1 * sv1.y + m2 * sv1.z + m3 * sv1.w;
        acc[2] += m0 * sv2.x + m1 * sv2.y + m2 * sv2.z + m3 * sv2.w;
        acc[3] += m0 * sv3.x + m1 * sv3.y + m2 * sv3.z + m3 * sv3.w;
    }
    if (o < OO) {
        const float cc = c2[o];
#pragma unroll
        for (int m = 0; m < 4; ++m) {
            const int t = t0 + tl + 4 * m;
            out[(size_t)t * OO + o] = acc[m] + cc;
        }
    }
}

extern "C" void kernel_launch(void* const* d_in, const int* in_sizes, int n_in,
                              void* d_out, int out_size, void* d_ws, size_t ws_size,
                              hipStream_t stream)
{
    const float* x    = (const float*)d_in[0];
    const float* Win  = (const float*)d_in[1];
    const float* W    = (const float*)d_in[2];
    const float* fc1w = (const float*)d_in[3];
    const float* fc1b = (const float*)d_in[4];
    const float* fc2w = (const float*)d_in[5];
    const float* fc2b = (const float*)d_in[6];
    float* out = (float*)d_out;

    if (ws_size < WS_NEED) return;

    char*  ws     = (char*)d_ws;
    float* states = (float*)ws;
    float* Mt     = (float*)(ws + STATES_BYTES);
    float* c2     = (float*)(ws + C2_OFF);
    float* rs     = (float*)(ws + RS_OFF);

    // Sentinel init: 0.0f < 0.5f means "not ready" for every h value.
    // (Kept despite harness 0xAA poison: rocprof replays may not re-poison,
    //  and counters from a sentinel-pre-satisfied replay would be garbage.)
    hipMemsetAsync(states, 0, STATES_BYTES, stream);

    k_rowsum<<<HH, 256, 0, stream>>>(fc1w, rs);
    k_mt<<<RR, 64, 0, stream>>>(fc1w, fc2w, Mt);
    k_c2<<<1, 64, 0, stream>>>(fc2w, fc2b, fc1b, rs, c2);

    scan_kernel<<<NBLK, NTHR, 0, stream>>>(x, Win, W, states);

    out_kernel<<<SS / TT, 256, 0, stream>>>(states, Mt, c2, out);
}

// Round 4
// 22970.886 us; speedup vs baseline: 4.2195x; 1.3180x over previous
//
#include <hip/hip_runtime.h>
#include <math.h>

// Echo-state network: sequential scan with dense 2048x2048 matvec per step.
// R4 design:
//  - KEY FIX: R2/R3 showed VGPR_Count=56/64 -> the compiler was NOT keeping
//    the per-thread W fragment in registers (it re-fetched 64 floats/lane
//    from L2 every step, ~2000cy/step hidden cost). Now __launch_bounds__
//    (512,2) raises the VGPR cap to 256 so the float4 W fragments stay
//    register-resident. Consume phase = 8 ds_read_b128 + 64 reg-FMAs.
//  - Geometry: 128 blocks x 512 thr (8 waves). Each wave owns 2 rows;
//    each lane holds cols {4l+j+256m} of both rows as float4 w0q[8],w1q[8].
//    Halves redundant LLC readers per line vs 256 blocks (poll contention).
//  - h broadcast: block-cooperative poll-load of 2048 h words (4/thread,
//    coalesced) with straggler-only batched retry, published to a
//    double-buffered LDS tile; ONE __syncthreads per step.
//  - Sentinel sync: h stored biased +2 (ready iff >= 0.5); memset-0 and the
//    harness 0xAA poison (-3e-13) both read not-ready. No fences needed.
//  - fc1/fc2 collapse: M = fc2_w@fc1_w, c2 = fc2_w@fc1_b + fc2_b - 2*rowsum(M)
//    (the -2 un-biases stored states). Phase 3: GEMM states @ Mt(2048x64pad).

#define SS 16384
#define II 64
#define RR 2048
#define HH 128
#define OO 50
#define OP 64          // padded output dim
#define NBLK 128
#define NTHR 512
#define RPB 16         // rows per block (2 per wave)
#define TT 16          // timesteps per block in out_kernel

static const size_t STATES_BYTES = (size_t)SS * RR * 4;        // 134217728
static const size_t MT_BYTES     = (size_t)RR * OP * 4;        // 524288
static const size_t C2_OFF       = STATES_BYTES + MT_BYTES;
static const size_t RS_OFF       = C2_OFF + 256;
static const size_t WS_NEED      = RS_OFF + 512 + 256;

// ---------------------------------------------------------------------------
// Persistent scan kernel. Wave w of block b owns rows R0=b*16+2w, R0+1.
// Lane l holds W[R0..R0+1][4l+j+256m] (j=0..3, m=0..7) in registers.
// ---------------------------------------------------------------------------
__global__ __launch_bounds__(NTHR, 2)
void scan_kernel(const float* __restrict__ x,
                 const float* __restrict__ Win,
                 const float* __restrict__ W,
                 float* __restrict__ states)
{
    const int tid  = threadIdx.x;
    const int blk  = blockIdx.x;
    const int wave = tid >> 6;              // 0..7
    const int lane = tid & 63;
    const int R0   = blk * RPB + wave * 2;

    // W fragments in registers (float4: 16B global loads, 16B LDS reads later)
    float4 w0q[8], w1q[8];
#pragma unroll
    for (int m = 0; m < 8; ++m) {
        w0q[m] = *(const float4*)&W[(size_t)R0       * RR + 4 * lane + 256 * m];
        w1q[m] = *(const float4*)&W[(size_t)(R0 + 1) * RR + 4 * lane + 256 * m];
    }
    // Input projection fragments (II == 64 == lanes)
    const float win0 = Win[(size_t)R0       * II + lane];
    const float win1 = Win[(size_t)(R0 + 1) * II + lane];

    __shared__ float hbuf[2][RR];   // double-buffered unbiased h tile

    const int   p    = lane & 1;    // even lanes track row R0, odd R0+1
    float       hold = 0.f;

    for (int t = 0; t < SS; ++t) {
        // x load: independent of h; issued before the poll hides its latency
        const float xv = x[(size_t)t * II + lane];
        float acc0 = win0 * xv;
        float acc1 = win1 * xv;

        if (t > 0) {
            const float* hp = states + (size_t)(t - 1) * RR;
            float* sb = hbuf[(t - 1) & 1];
            float v[4];
            // First pass: 4 coalesced loads/thread (block covers all 2048)
#pragma unroll
            for (int k = 0; k < 4; ++k)
                v[k] = __hip_atomic_load(hp + tid + 512 * k,
                                         __ATOMIC_RELAXED, __HIP_MEMORY_SCOPE_AGENT);
            // Straggler-only batched retry (exec-masked, 1 waitcnt/round)
            for (;;) {
                float mn = fminf(fminf(v[0], v[1]), fminf(v[2], v[3]));
                if (mn >= 0.5f) break;   // ready values are in (1,3)
#pragma unroll
                for (int k = 0; k < 4; ++k)
                    if (v[k] < 0.5f)
                        v[k] = __hip_atomic_load(hp + tid + 512 * k,
                                                 __ATOMIC_RELAXED, __HIP_MEMORY_SCOPE_AGENT);
            }
            // Publish unbiased values (stride-512: bank=tid%32, 2-way, free)
#pragma unroll
            for (int k = 0; k < 4; ++k)
                sb[tid + 512 * k] = v[k] - 2.0f;
            __syncthreads();           // the ONLY barrier per step

            // Consume: 8 x ds_read_b128, contiguous per lane (conflict-free)
            const float4* sq = (const float4*)sb;
#pragma unroll
            for (int m = 0; m < 8; ++m) {
                const float4 q = sq[lane + 64 * m];
                acc0 += w0q[m].x * q.x + w0q[m].y * q.y
                      + w0q[m].z * q.z + w0q[m].w * q.w;
                acc1 += w1q[m].x * q.x + w1q[m].y * q.y
                      + w1q[m].z * q.z + w1q[m].w * q.w;
            }
        }

        // In-wave butterfly: all lanes end with both full row sums
#pragma unroll
        for (int off = 1; off <= 32; off <<= 1) {
            acc0 += __shfl_xor(acc0, off, 64);
            acc1 += __shfl_xor(acc1, off, 64);
        }

        // Each lane finishes ONE row (by parity); lanes 0,1 store.
        float u = p ? acc1 : acc0;
        u = fminf(fmaxf(u, -20.f), 20.f);
        const float e  = __expf(2.f * u);
        const float th = (e - 1.f) / (e + 1.f);
        const float hn = 0.5f * hold + 0.5f * th;
        hold = hn;
        if (lane < 2)
            __hip_atomic_store(&states[(size_t)t * RR + R0 + lane], hn + 2.0f,
                               __ATOMIC_RELAXED, __HIP_MEMORY_SCOPE_AGENT);
    }
}

// ---------------------------------------------------------------------------
// rowsum of fc1_w rows: rs[h] = sum_r fc1_w[h][r]
// ---------------------------------------------------------------------------
__global__ void k_rowsum(const float* __restrict__ fc1w, float* __restrict__ rs)
{
    const int h = blockIdx.x;
    const int tid = threadIdx.x;
    float a = 0.f;
    for (int r = tid; r < RR; r += 256) a += fc1w[(size_t)h * RR + r];
#pragma unroll
    for (int off = 1; off <= 32; off <<= 1) a += __shfl_xor(a, off, 64);
    __shared__ float red[4];
    if ((tid & 63) == 0) red[tid >> 6] = a;
    __syncthreads();
    if (tid == 0) rs[h] = red[0] + red[1] + red[2] + red[3];
}

// ---------------------------------------------------------------------------
// Mt[r][o] = sum_h fc2_w[o][h] * fc1_w[h][r]   (o padded to 64, zeros)
// ---------------------------------------------------------------------------
__global__ void k_mt(const float* __restrict__ fc1w,
                     const float* __restrict__ fc2w,
                     float* __restrict__ Mt)
{
    __shared__ float w2[OO][HH + 1];
    const int o = threadIdx.x;         // 64
    const int r = blockIdx.x;          // 2048
    for (int i = o; i < OO * HH; i += 64) w2[i / HH][i % HH] = fc2w[i];
    __syncthreads();
    float a = 0.f;
    if (o < OO) {
        for (int h = 0; h < HH; ++h)
            a += w2[o][h] * fc1w[(size_t)h * RR + r];
    }
    Mt[r * OP + o] = a;
}

// ---------------------------------------------------------------------------
// c2[o] = fc2_b[o] + sum_h fc2_w[o][h]*(fc1_b[h] - 2*rs[h])
// ---------------------------------------------------------------------------
__global__ void k_c2(const float* __restrict__ fc2w,
                     const float* __restrict__ fc2b,
                     const float* __restrict__ fc1b,
                     const float* __restrict__ rs,
                     float* __restrict__ c2)
{
    const int o = threadIdx.x;  // 64
    float a = 0.f;
    if (o < OO) {
        for (int h = 0; h < HH; ++h)
            a += fc2w[o * HH + h] * (fc1b[h] - 2.f * rs[h]);
        a += fc2b[o];
    }
    c2[o] = a;
}

// ---------------------------------------------------------------------------
// out[t][o] = sum_r Mt[r][o] * states_biased[t][r] + c2[o]
// ---------------------------------------------------------------------------
__global__ __launch_bounds__(256)
void out_kernel(const float* __restrict__ sb,
                const float* __restrict__ Mt,
                const float* __restrict__ c2,
                float* __restrict__ out)
{
    const int tid = threadIdx.x;
    const int o   = tid & 63;
    const int tl  = tid >> 6;          // 0..3
    const int t0  = blockIdx.x * TT;
    float acc[4] = {0.f, 0.f, 0.f, 0.f};
    const float* s0 = sb + (size_t)t0 * RR;

    for (int r = 0; r < RR; r += 4) {
        float4 sv0 = *(const float4*)(s0 + (size_t)(tl + 0)  * RR + r);
        float4 sv1 = *(const float4*)(s0 + (size_t)(tl + 4)  * RR + r);
        float4 sv2 = *(const float4*)(s0 + (size_t)(tl + 8)  * RR + r);
        float4 sv3 = *(const float4*)(s0 + (size_t)(tl + 12) * RR + r);
        float m0 = Mt[(r + 0) * OP + o];
        float m1 = Mt[(r + 1) * OP + o];
        float m2 = Mt[(r + 2) * OP + o];
        float m3 = Mt[(r + 3) * OP + o];
        acc[0] += m0 * sv0.x + m1 * sv0.y + m2 * sv0.z + m3 * sv0.w;
        acc[1] += m0 * sv1.x + m1 * sv1.y + m2 * sv1.z + m3 * sv1.w;
        acc[2] += m0 * sv2.x + m1 * sv2.y + m2 * sv2.z + m3 * sv2.w;
        acc[3] += m0 * sv3.x + m1 * sv3.y + m2 * sv3.z + m3 * sv3.w;
    }
    if (o < OO) {
        const float cc = c2[o];
#pragma unroll
        for (int m = 0; m < 4; ++m) {
            const int t = t0 + tl + 4 * m;
            out[(size_t)t * OO + o] = acc[m] + cc;
        }
    }
}

extern "C" void kernel_launch(void* const* d_in, const int* in_sizes, int n_in,
                              void* d_out, int out_size, void* d_ws, size_t ws_size,
                              hipStream_t stream)
{
    const float* x    = (const float*)d_in[0];
    const float* Win  = (const float*)d_in[1];
    const float* W    = (const float*)d_in[2];
    const float* fc1w = (const float*)d_in[3];
    const float* fc1b = (const float*)d_in[4];
    const float* fc2w = (const float*)d_in[5];
    const float* fc2b = (const float*)d_in[6];
    float* out = (float*)d_out;

    if (ws_size < WS_NEED) return;

    char*  ws     = (char*)d_ws;
    float* states = (float*)ws;
    float* Mt     = (float*)(ws + STATES_BYTES);
    float* c2     = (float*)(ws + C2_OFF);
    float* rs     = (float*)(ws + RS_OFF);

    // Sentinel init: 0.0f < 0.5f means "not ready" for every h value.
    hipMemsetAsync(states, 0, STATES_BYTES, stream);

    k_rowsum<<<HH, 256, 0, stream>>>(fc1w, rs);
    k_mt<<<RR, 64, 0, stream>>>(fc1w, fc2w, Mt);
    k_c2<<<1, 64, 0, stream>>>(fc2w, fc2b, fc1b, rs, c2);

    scan_kernel<<<NBLK, NTHR, 0, stream>>>(x, Win, W, states);

    out_kernel<<<SS / TT, 256, 0, stream>>>(states, Mt, c2, out);
}

// Round 5
// 22870.335 us; speedup vs baseline: 4.2381x; 1.0044x over previous
//
#include <hip/hip_runtime.h>
#include <math.h>

// Echo-state network: sequential scan with dense 2048x2048 matvec per step.
// R5 design:
//  - R2/R3/R4 all showed VGPR_Count=52..64: the AMDGPU allocator SINKS the
//    loop-invariant W loads into the t-loop (remat to minimize pressure),
//    re-fetching W from L2 every step. launch_bounds alone didn't stop it.
//    FIX: empty inline-asm "+v" pins on every W component make the values
//    opaque -> cannot be rematerialized -> must stay in VGPRs. Plus
//    amdgpu_waves_per_eu(2,2) so the allocator targets exactly 2 waves/EU.
//    Attribution signal: VGPR_Count must jump to >=96.
//  - Geometry: 128 blocks x 512 thr (8 waves). Wave w owns rows R0=b*16+2w,
//    R0+1; lane l holds cols {4l+j+256m} of both rows as float4 w0q[8],w1q[8].
//  - h broadcast: block-cooperative poll-load of 2048 h words (4/thread,
//    coalesced stride-512) with straggler-only batched retry, published to a
//    double-buffered LDS tile; ONE __syncthreads per step.
//  - Butterfly halved: parity-combine (1 shfl) then 5 xor-shfls (was 12).
//  - Sentinel sync: h stored biased +2 (ready iff >= 0.5); memset-0 and the
//    harness 0xAA poison (-3e-13) both read not-ready. No fences needed.
//  - fc1/fc2 collapse: M = fc2_w@fc1_w, c2 = fc2_w@fc1_b + fc2_b - 2*rowsum(M)
//    (the -2 un-biases stored states). Phase 3: GEMM states @ Mt(2048x64pad).

#define SS 16384
#define II 64
#define RR 2048
#define HH 128
#define OO 50
#define OP 64          // padded output dim
#define NBLK 128
#define NTHR 512
#define RPB 16         // rows per block (2 per wave)
#define TT 16          // timesteps per block in out_kernel

static const size_t STATES_BYTES = (size_t)SS * RR * 4;        // 134217728
static const size_t MT_BYTES     = (size_t)RR * OP * 4;        // 524288
static const size_t C2_OFF       = STATES_BYTES + MT_BYTES;
static const size_t RS_OFF       = C2_OFF + 256;
static const size_t WS_NEED      = RS_OFF + 512 + 256;

// Opaque register pin: forbids rematerialization/sinking of the value's def.
#define PIN4(q) asm volatile("" : "+v"((q).x), "+v"((q).y), "+v"((q).z), "+v"((q).w))

// ---------------------------------------------------------------------------
// Persistent scan kernel. Wave w of block b owns rows R0=b*16+2w, R0+1.
// ---------------------------------------------------------------------------
__global__ __launch_bounds__(NTHR, 2) __attribute__((amdgpu_waves_per_eu(2, 2)))
void scan_kernel(const float* __restrict__ x,
                 const float* __restrict__ Win,
                 const float* __restrict__ W,
                 float* __restrict__ states)
{
    const int tid  = threadIdx.x;
    const int blk  = blockIdx.x;
    const int wave = tid >> 6;              // 0..7
    const int lane = tid & 63;
    const int R0   = blk * RPB + wave * 2;

    // W fragments in registers; PIN4 makes them non-rematerializable.
    float4 w0q[8], w1q[8];
#pragma unroll
    for (int m = 0; m < 8; ++m) {
        w0q[m] = *(const float4*)&W[(size_t)R0       * RR + 4 * lane + 256 * m];
        w1q[m] = *(const float4*)&W[(size_t)(R0 + 1) * RR + 4 * lane + 256 * m];
        PIN4(w0q[m]);
        PIN4(w1q[m]);
    }
    // Input projection fragments (II == 64 == lanes)
    float win0 = Win[(size_t)R0       * II + lane];
    float win1 = Win[(size_t)(R0 + 1) * II + lane];
    asm volatile("" : "+v"(win0), "+v"(win1));

    __shared__ float hbuf[2][RR];   // double-buffered unbiased h tile

    const int   p    = lane & 1;    // even lanes track row R0, odd R0+1
    float       hold = 0.f;

    for (int t = 0; t < SS; ++t) {
        // x load: independent of h; issued before the poll hides its latency
        const float xv = x[(size_t)t * II + lane];
        float acc0 = win0 * xv;
        float acc1 = win1 * xv;

        if (t > 0) {
            const float* hp = states + (size_t)(t - 1) * RR;
            float* sb = hbuf[(t - 1) & 1];
            float v[4];
            // First pass: 4 coalesced loads/thread (block covers all 2048)
#pragma unroll
            for (int k = 0; k < 4; ++k)
                v[k] = __hip_atomic_load(hp + tid + 512 * k,
                                         __ATOMIC_RELAXED, __HIP_MEMORY_SCOPE_AGENT);
            // Straggler-only batched retry (exec-masked, 1 waitcnt/round)
            for (;;) {
                float mn = fminf(fminf(v[0], v[1]), fminf(v[2], v[3]));
                if (mn >= 0.5f) break;   // ready values are in (1,3)
#pragma unroll
                for (int k = 0; k < 4; ++k)
                    if (v[k] < 0.5f)
                        v[k] = __hip_atomic_load(hp + tid + 512 * k,
                                                 __ATOMIC_RELAXED, __HIP_MEMORY_SCOPE_AGENT);
            }
            // Publish unbiased values (stride-512: 2-way bank alias, free)
#pragma unroll
            for (int k = 0; k < 4; ++k)
                sb[tid + 512 * k] = v[k] - 2.0f;
            __syncthreads();           // the ONLY barrier per step

            // Consume: 8 x ds_read_b128, contiguous per lane (conflict-free)
            const float4* sq = (const float4*)sb;
#pragma unroll
            for (int m = 0; m < 8; ++m) {
                const float4 q = sq[lane + 64 * m];
                acc0 += w0q[m].x * q.x + w0q[m].y * q.y
                      + w0q[m].z * q.z + w0q[m].w * q.w;
                acc1 += w1q[m].x * q.x + w1q[m].y * q.y
                      + w1q[m].z * q.z + w1q[m].w * q.w;
            }
        }

        // Parity-combine then 5-level butterfly (6 shfls total, was 12):
        // even lanes end with full row-R0 sum, odd lanes with row-R0+1.
        {
            const float sel = p ? acc0 : acc1;     // the row NOT owned
            const float own = p ? acc1 : acc0;     // the row owned
            float a = own + __shfl_xor(sel, 1, 64);
#pragma unroll
            for (int off = 2; off <= 32; off <<= 1)
                a += __shfl_xor(a, off, 64);
            // tanh + leaky update for row R0+p
            float u = fminf(fmaxf(a, -20.f), 20.f);
            const float e  = __expf(2.f * u);
            const float th = (e - 1.f) / (e + 1.f);
            const float hn = 0.5f * hold + 0.5f * th;
            hold = hn;
            if (lane < 2)
                __hip_atomic_store(&states[(size_t)t * RR + R0 + lane], hn + 2.0f,
                                   __ATOMIC_RELAXED, __HIP_MEMORY_SCOPE_AGENT);
        }
    }
}

// ---------------------------------------------------------------------------
// rowsum of fc1_w rows: rs[h] = sum_r fc1_w[h][r]
// ---------------------------------------------------------------------------
__global__ void k_rowsum(const float* __restrict__ fc1w, float* __restrict__ rs)
{
    const int h = blockIdx.x;
    const int tid = threadIdx.x;
    float a = 0.f;
    for (int r = tid; r < RR; r += 256) a += fc1w[(size_t)h * RR + r];
#pragma unroll
    for (int off = 1; off <= 32; off <<= 1) a += __shfl_xor(a, off, 64);
    __shared__ float red[4];
    if ((tid & 63) == 0) red[tid >> 6] = a;
    __syncthreads();
    if (tid == 0) rs[h] = red[0] + red[1] + red[2] + red[3];
}

// ---------------------------------------------------------------------------
// Mt[r][o] = sum_h fc2_w[o][h] * fc1_w[h][r]   (o padded to 64, zeros)
// ---------------------------------------------------------------------------
__global__ void k_mt(const float* __restrict__ fc1w,
                     const float* __restrict__ fc2w,
                     float* __restrict__ Mt)
{
    __shared__ float w2[OO][HH + 1];
    const int o = threadIdx.x;         // 64
    const int r = blockIdx.x;          // 2048
    for (int i = o; i < OO * HH; i += 64) w2[i / HH][i % HH] = fc2w[i];
    __syncthreads();
    float a = 0.f;
    if (o < OO) {
        for (int h = 0; h < HH; ++h)
            a += w2[o][h] * fc1w[(size_t)h * RR + r];
    }
    Mt[r * OP + o] = a;
}

// ---------------------------------------------------------------------------
// c2[o] = fc2_b[o] + sum_h fc2_w[o][h]*(fc1_b[h] - 2*rs[h])
// ---------------------------------------------------------------------------
__global__ void k_c2(const float* __restrict__ fc2w,
                     const float* __restrict__ fc2b,
                     const float* __restrict__ fc1b,
                     const float* __restrict__ rs,
                     float* __restrict__ c2)
{
    const int o = threadIdx.x;  // 64
    float a = 0.f;
    if (o < OO) {
        for (int h = 0; h < HH; ++h)
            a += fc2w[o * HH + h] * (fc1b[h] - 2.f * rs[h]);
        a += fc2b[o];
    }
    c2[o] = a;
}

// ---------------------------------------------------------------------------
// out[t][o] = sum_r Mt[r][o] * states_biased[t][r] + c2[o]
// ---------------------------------------------------------------------------
__global__ __launch_bounds__(256)
void out_kernel(const float* __restrict__ sb,
                const float* __restrict__ Mt,
                const float* __restrict__ c2,
                float* __restrict__ out)
{
    const int tid = threadIdx.x;
    const int o   = tid & 63;
    const int tl  = tid >> 6;          // 0..3
    const int t0  = blockIdx.x * TT;
    float acc[4] = {0.f, 0.f, 0.f, 0.f};
    const float* s0 = sb + (size_t)t0 * RR;

    for (int r = 0; r < RR; r += 4) {
        float4 sv0 = *(const float4*)(s0 + (size_t)(tl + 0)  * RR + r);
        float4 sv1 = *(const float4*)(s0 + (size_t)(tl + 4)  * RR + r);
        float4 sv2 = *(const float4*)(s0 + (size_t)(tl + 8)  * RR + r);
        float4 sv3 = *(const float4*)(s0 + (size_t)(tl + 12) * RR + r);
        float m0 = Mt[(r + 0) * OP + o];
        float m1 = Mt[(r + 1) * OP + o];
        float m2 = Mt[(r + 2) * OP + o];
        float m3 = Mt[(r + 3) * OP + o];
        acc[0] += m0 * sv0.x + m1 * sv0.y + m2 * sv0.z + m3 * sv0.w;
        acc[1] += m0 * sv1.x + m1 * sv1.y + m2 * sv1.z + m3 * sv1.w;
        acc[2] += m0 * sv2.x + m1 * sv2.y + m2 * sv2.z + m3 * sv2.w;
        acc[3] += m0 * sv3.x + m1 * sv3.y + m2 * sv3.z + m3 * sv3.w;
    }
    if (o < OO) {
        const float cc = c2[o];
#pragma unroll
        for (int m = 0; m < 4; ++m) {
            const int t = t0 + tl + 4 * m;
            out[(size_t)t * OO + o] = acc[m] + cc;
        }
    }
}

extern "C" void kernel_launch(void* const* d_in, const int* in_sizes, int n_in,
                              void* d_out, int out_size, void* d_ws, size_t ws_size,
                              hipStream_t stream)
{
    const float* x    = (const float*)d_in[0];
    const float* Win  = (const float*)d_in[1];
    const float* W    = (const float*)d_in[2];
    const float* fc1w = (const float*)d_in[3];
    const float* fc1b = (const float*)d_in[4];
    const float* fc2w = (const float*)d_in[5];
    const float* fc2b = (const float*)d_in[6];
    float* out = (float*)d_out;

    if (ws_size < WS_NEED) return;

    char*  ws     = (char*)d_ws;
    float* states = (float*)ws;
    float* Mt     = (float*)(ws + STATES_BYTES);
    float* c2     = (float*)(ws + C2_OFF);
    float* rs     = (float*)(ws + RS_OFF);

    // Sentinel init: 0.0f < 0.5f means "not ready" for every h value.
    hipMemsetAsync(states, 0, STATES_BYTES, stream);

    k_rowsum<<<HH, 256, 0, stream>>>(fc1w, rs);
    k_mt<<<RR, 64, 0, stream>>>(fc1w, fc2w, Mt);
    k_c2<<<1, 64, 0, stream>>>(fc2w, fc2b, fc1b, rs, c2);

    scan_kernel<<<NBLK, NTHR, 0, stream>>>(x, Win, W, states);

    out_kernel<<<SS / TT, 256, 0, stream>>>(states, Mt, c2, out);
}